// Round 1
// baseline (64.662 us; speedup 1.0000x reference)
//
#include <hip/hip_runtime.h>
#include <hip/hip_bf16.h>

typedef __attribute__((ext_vector_type(8))) short bf16x8;
typedef __attribute__((ext_vector_type(4))) float f32x4;

#define D_K    256
#define WH     784
#define P_REAL 511
#define P_PAD  512
#define C_OUT  200
#define NLEAF  512
#define TDEPTH 9

#define NT      64
#define NTILES  13          // 12*64 + 16 (tail clamped to duplicate columns)
#define XS_STRIDE 288       // ushorts per LDS n-row (256 + 32 pad, multiple of 32)

// workspace offsets (bytes)
#define WS_PROTO 0
#define WS_P2    (512*256*2)          // 262144
#define WS_S     (WS_P2 + 512*4)      // 264192
#define WS_DS    (WS_S + 128*512*4)   // 526336
// total: 526336 + 512*200*4 = 935936 bytes

static __device__ __forceinline__ unsigned short f2bf(float x) {
    union { float f; unsigned int u; } v; v.f = x;
    unsigned int r = v.u + 0x7FFFu + ((v.u >> 16) & 1u);   // round-to-nearest-even
    return (unsigned short)(r >> 16);
}

// swizzled LDS index (ushort units): bijective within each 256-elem row,
// keeps 8B write / 16B read alignment, spreads banks for both phases
static __device__ __forceinline__ int xs_idx(int n, int k) {
    return (n * XS_STRIDE + k) ^ ((n & 0x1C) << 1);
}

// --- prep: proto -> bf16(-2p) padded to 512 rows, plus p2 = sum(p^2) -------
__global__ __launch_bounds__(64)
void prep_kernel(const float* __restrict__ protos,
                 unsigned short* __restrict__ pb,
                 float* __restrict__ p2) {
    int p = blockIdx.x;        // 0..511
    int l = threadIdx.x;       // 0..63
    f32x4 v = {0.f, 0.f, 0.f, 0.f};
    if (p < P_REAL)
        v = *reinterpret_cast<const f32x4*>(protos + (size_t)p * D_K + 4 * l);
    ushort4 w;
    w.x = f2bf(-2.f * v[0]); w.y = f2bf(-2.f * v[1]);
    w.z = f2bf(-2.f * v[2]); w.w = f2bf(-2.f * v[3]);
    *reinterpret_cast<ushort4*>(pb + (size_t)p * D_K + 4 * l) = w;
    float s = v[0]*v[0] + v[1]*v[1] + v[2]*v[2] + v[3]*v[3];
#pragma unroll
    for (int m = 32; m >= 1; m >>= 1) s += __shfl_xor(s, m, 64);
    if (l == 0) p2[p] = s;
}

// --- softmax of leaf_params rows ------------------------------------------
__global__ __launch_bounds__(64)
void softmax_kernel(const float* __restrict__ lp, float* __restrict__ ds) {
    int row = blockIdx.x;      // 0..511
    int lane = threadIdx.x;
    float v[4];
    float mx = -3.4e38f;
#pragma unroll
    for (int i = 0; i < 4; ++i) {
        int c = lane + 64 * i;
        v[i] = (c < C_OUT) ? lp[(size_t)row * C_OUT + c] : -3.4e38f;
        mx = fmaxf(mx, v[i]);
    }
#pragma unroll
    for (int m = 32; m >= 1; m >>= 1) mx = fmaxf(mx, __shfl_xor(mx, m, 64));
    float sum = 0.f;
#pragma unroll
    for (int i = 0; i < 4; ++i) {
        int c = lane + 64 * i;
        if (c < C_OUT) { v[i] = expf(v[i] - mx); sum += v[i]; }
    }
#pragma unroll
    for (int m = 32; m >= 1; m >>= 1) sum += __shfl_xor(sum, m, 64);
    float inv = 1.f / sum;
#pragma unroll
    for (int i = 0; i < 4; ++i) {
        int c = lane + 64 * i;
        if (c < C_OUT) ds[(size_t)row * C_OUT + c] = v[i] * inv;
    }
}

// --- main: similarities[b][p] = exp(-sqrt(|min_wh(x2 - 2xp) + p2|+1e-14)) --
__global__ __launch_bounds__(512, 2)
void proto_min_kernel(const float* __restrict__ xs,
                      const unsigned short* __restrict__ pb,
                      const float* __restrict__ p2,
                      float* __restrict__ sbuf) {
    __shared__ unsigned short Xs[NT * XS_STRIDE];   // 36864 B
    __shared__ float x2buf[8][16][4];               // 2048 B

    const int tid  = threadIdx.x;
    const int wv   = tid >> 6;
    const int lane = tid & 63;
    const int g    = lane >> 4;   // 0..3
    const int lr   = lane & 15;   // 0..15

    // XCD-pairing swizzle: both p-halves of one b land on the same XCD
    const int xg   = blockIdx.x;
    const int xcd  = xg & 7;
    const int slot = xg >> 3;
    const int ph   = slot & 1;
    const int bIdx = xcd + 8 * (slot >> 1);   // 0..127
    const int p0   = ph * 256;

    const float* xb = xs + (size_t)bIdx * (D_K * WH);

    // A fragments: -2*proto bf16, wave's 32 rows x full K, resident in regs
    bf16x8 af[2][8];
#pragma unroll
    for (int mf = 0; mf < 2; ++mf) {
        const unsigned short* rp = pb + (size_t)(p0 + 32*wv + 16*mf + lr) * D_K + 8*g;
#pragma unroll
        for (int ks = 0; ks < 8; ++ks)
            af[mf][ks] = *reinterpret_cast<const bf16x8*>(rp + 32*ks);
    }

    const int n4  = tid & 15;   // n-quad within tile
    const int kq0 = tid >> 4;   // k-quads kq0 and kq0+32

    float rmin[2][4];
#pragma unroll
    for (int mf = 0; mf < 2; ++mf)
#pragma unroll
        for (int r = 0; r < 4; ++r) rmin[mf][r] = 3.0e38f;

    // prefetch tile 0
    f32x4 ld[2][4];
    {
        int colb = 4 * n4;
#pragma unroll
        for (int i = 0; i < 2; ++i) {
            const float* rowp = xb + (size_t)(4*(kq0 + 32*i)) * WH + colb;
#pragma unroll
            for (int r = 0; r < 4; ++r)
                ld[i][r] = *reinterpret_cast<const f32x4*>(rowp + r * WH);
        }
    }

    for (int t = 0; t < NTILES; ++t) {
        // ---- convert + 4x4 transpose write + x2 partials (from fp32 regs)
        f32x4 x2q = {0.f, 0.f, 0.f, 0.f};
#pragma unroll
        for (int i = 0; i < 2; ++i) {
            int kq = kq0 + 32*i;
#pragma unroll
            for (int r = 0; r < 4; ++r) {
                f32x4 v = ld[i][r];
                x2q[0] += v[0]*v[0]; x2q[1] += v[1]*v[1];
                x2q[2] += v[2]*v[2]; x2q[3] += v[3]*v[3];
            }
#pragma unroll
            for (int c = 0; c < 4; ++c) {
                ushort4 w;
                w.x = f2bf(ld[i][0][c]);
                w.y = f2bf(ld[i][1][c]);
                w.z = f2bf(ld[i][2][c]);
                w.w = f2bf(ld[i][3][c]);
                *reinterpret_cast<ushort4*>(&Xs[xs_idx(4*n4 + c, 4*kq)]) = w;
            }
        }
        // reduce x2 over the 4 lanes sharing n4 (same lr across l, l^16, l^32, l^48)
#pragma unroll
        for (int c = 0; c < 4; ++c) {
            x2q[c] += __shfl_xor(x2q[c], 16, 64);
            x2q[c] += __shfl_xor(x2q[c], 32, 64);
        }
        if (lane < 16)
            *reinterpret_cast<f32x4*>(&x2buf[wv][lane][0]) = x2q;

        __syncthreads();

        // ---- T14: issue next tile's global loads before the MFMA phase
        if (t + 1 < NTILES) {
            int colb = (t + 1) * NT + 4 * n4;
            if (colb > WH - 4) colb = WH - 4;   // tail: duplicate valid columns
#pragma unroll
            for (int i = 0; i < 2; ++i) {
                const float* rowp = xb + (size_t)(4*(kq0 + 32*i)) * WH + colb;
#pragma unroll
                for (int r = 0; r < 4; ++r)
                    ld[i][r] = *reinterpret_cast<const f32x4*>(rowp + r * WH);
            }
        }

        // ---- x2 for this lane's columns (n = 16*nf + lr)
        float x2v[4];
#pragma unroll
        for (int nf = 0; nf < 4; ++nf) {
            int nn = 16*nf + lr;
            float s = 0.f;
#pragma unroll
            for (int w = 0; w < 8; ++w) s += x2buf[w][nn >> 2][nn & 3];
            x2v[nf] = s;
        }

        // ---- GEMM: acc = (-2P) * X for this tile
        f32x4 acc[2][4];
#pragma unroll
        for (int mf = 0; mf < 2; ++mf)
#pragma unroll
            for (int nf = 0; nf < 4; ++nf)
                acc[mf][nf] = (f32x4){0.f, 0.f, 0.f, 0.f};

#pragma unroll
        for (int ks = 0; ks < 8; ++ks) {
            bf16x8 bfr[4];
#pragma unroll
            for (int nf = 0; nf < 4; ++nf)
                bfr[nf] = *reinterpret_cast<const bf16x8*>(&Xs[xs_idx(16*nf + lr, 32*ks + 8*g)]);
#pragma unroll
            for (int mf = 0; mf < 2; ++mf)
#pragma unroll
                for (int nf = 0; nf < 4; ++nf)
                    acc[mf][nf] = __builtin_amdgcn_mfma_f32_16x16x32_bf16(
                        af[mf][ks], bfr[nf], acc[mf][nf], 0, 0, 0);
        }

        // ---- running min over this tile's columns
#pragma unroll
        for (int nf = 0; nf < 4; ++nf)
#pragma unroll
            for (int mf = 0; mf < 2; ++mf)
#pragma unroll
                for (int r = 0; r < 4; ++r)
                    rmin[mf][r] = fminf(rmin[mf][r], x2v[nf] + acc[mf][nf][r]);

        __syncthreads();
    }

    // min across the 16 column-lanes (flips only lr bits; g preserved)
#pragma unroll
    for (int mf = 0; mf < 2; ++mf)
#pragma unroll
        for (int r = 0; r < 4; ++r) {
            float v = rmin[mf][r];
#pragma unroll
            for (int m = 1; m <= 8; m <<= 1)
                v = fminf(v, __shfl_xor(v, m, 64));
            rmin[mf][r] = v;
        }

    if (lr == 0) {
#pragma unroll
        for (int mf = 0; mf < 2; ++mf)
#pragma unroll
            for (int r = 0; r < 4; ++r) {
                int p = p0 + 32*wv + 16*mf + 4*g + r;
                float sq = rmin[mf][r] + p2[p];
                float d = sqrtf(fabsf(sq) + 1e-14f);
                sbuf[(size_t)bIdx * P_PAD + p] = expf(-d);
            }
    }
}

// --- tree path products + pa @ ds -----------------------------------------
__global__ __launch_bounds__(256)
void out_kernel(const float* __restrict__ sbuf,
                const float* __restrict__ ds,
                float* __restrict__ out) {
    __shared__ float pa[NLEAF];
    int b = blockIdx.x;
    int t = threadIdx.x;
    const float* sb = sbuf + (size_t)b * P_PAD;
#pragma unroll
    for (int j = 0; j < 2; ++j) {
        int leaf = t + 256 * j;
        int node = 0;
        float prod = 1.f;
#pragma unroll
        for (int st = 0; st < TDEPTH; ++st) {
            int bit = (leaf >> (TDEPTH - 1 - st)) & 1;
            float sv = sb[node];
            prod *= bit ? sv : (1.f - sv);
            node = 2 * node + 1 + bit;
        }
        pa[leaf] = prod;
    }
    __syncthreads();
    if (t < C_OUT) {
        float a0 = 0.f, a1 = 0.f, a2 = 0.f, a3 = 0.f;
        for (int l = 0; l < NLEAF; l += 4) {
            a0 += pa[l + 0] * ds[(size_t)(l + 0) * C_OUT + t];
            a1 += pa[l + 1] * ds[(size_t)(l + 1) * C_OUT + t];
            a2 += pa[l + 2] * ds[(size_t)(l + 2) * C_OUT + t];
            a3 += pa[l + 3] * ds[(size_t)(l + 3) * C_OUT + t];
        }
        out[(size_t)b * C_OUT + t] = (a0 + a1) + (a2 + a3);
    }
}

extern "C" void kernel_launch(void* const* d_in, const int* in_sizes, int n_in,
                              void* d_out, int out_size, void* d_ws, size_t ws_size,
                              hipStream_t stream) {
    (void)in_sizes; (void)n_in; (void)out_size; (void)ws_size;
    const float* xs     = (const float*)d_in[0];
    const float* protos = (const float*)d_in[1];
    const float* lp     = (const float*)d_in[2];
    float* out = (float*)d_out;

    char* ws = (char*)d_ws;
    unsigned short* pb = (unsigned short*)(ws + WS_PROTO);
    float* p2   = (float*)(ws + WS_P2);
    float* sbuf = (float*)(ws + WS_S);
    float* dsm  = (float*)(ws + WS_DS);

    prep_kernel<<<512, 64, 0, stream>>>(protos, pb, p2);
    softmax_kernel<<<512, 64, 0, stream>>>(lp, dsm);
    proto_min_kernel<<<256, 512, 0, stream>>>(xs, pb, p2, sbuf);
    out_kernel<<<128, 256, 0, stream>>>(sbuf, dsm, out);
}